// Round 21
// baseline (115.796 us; speedup 1.0000x reference)
//
#include <hip/hip_runtime.h>

#define B_ 4
#define C_ 256
#define N_ 4096
#define LOG2E 1.4426950408889634f

typedef short short8 __attribute__((ext_vector_type(8)));
typedef short short4_ __attribute__((ext_vector_type(4)));
typedef float float4v __attribute__((ext_vector_type(4)));
typedef unsigned int uint2v __attribute__((ext_vector_type(2)));
typedef unsigned int u32;

__device__ inline unsigned short f2b(float x){
  unsigned u = __builtin_bit_cast(unsigned, x);
  u = u + 0x7FFFu + ((u >> 16) & 1u);
  return (unsigned short)(u >> 16);
}
__device__ inline float b2f(unsigned short s){
  return __builtin_bit_cast(float, ((u32)s) << 16);
}
__device__ inline u32 cvtpk(float lo, float hi){
  u32 r; asm("v_cvt_pk_bf16_f32 %0, %1, %2" : "=v"(r) : "v"(lo), "v"(hi)); return r;
}
__device__ inline void gload16(const void* g, void* l){
  __builtin_amdgcn_global_load_lds((const __attribute__((address_space(1))) u32*)g,
                                   (__attribute__((address_space(3))) u32*)l, 16, 0, 0);
}

// ---------------- fold BN into weights (log2e folded into Q path) ----------------
__global__ void fold_w_kernel(const float* __restrict__ wq, const float* __restrict__ wk,
    const float* __restrict__ wv,
    const float* gq, const float* bq, const float* mq, const float* vq,
    const float* gk, const float* bk, const float* mk, const float* vk,
    const float* gv, const float* bv, const float* mv, const float* vv,
    unsigned short* wqb, unsigned short* wkb, unsigned short* wvb,
    float* biasq, float* biask, float* biasv){
  int i = blockIdx.x*256 + threadIdx.x;   // 65536 threads
  int o = i >> 8;
  float sv = gv[o]*rsqrtf(vv[o]+1e-5f);
  wvb[i] = f2b(wv[i]*sv);
  if (i < 32*256){
    int oq = i >> 8;
    float sq = gq[oq]*rsqrtf(vq[oq]+1e-5f);
    wqb[i] = f2b(wq[i]*sq*LOG2E);
    float sk = gk[oq]*rsqrtf(vk[oq]+1e-5f);
    wkb[i] = f2b(wk[i]*sk);
  }
  if (i < 256) biasv[i] = bv[i] - mv[i]*(gv[i]*rsqrtf(vv[i]+1e-5f));
  if (i < 32){
    biasq[i] = (bq[i] - mq[i]*(gq[i]*rsqrtf(vq[i]+1e-5f)))*LOG2E;
    biask[i] = bk[i] - mk[i]*(gk[i]*rsqrtf(vk[i]+1e-5f));
  }
}

// ------- preprocessing (3-slice): z=0 upsample+Qconv (no x1u store) ;
//         z=1 x2 stage+K+V[0:128) ; z=2 x2 stage+V[128:256) -------
__global__ __launch_bounds__(256, 2)
void pre_kernel(const float* __restrict__ x1, const float* __restrict__ x2,
                const unsigned short* __restrict__ wqb,
                const unsigned short* __restrict__ wkb,
                const unsigned short* __restrict__ wvb,
                const float* __restrict__ biasq, const float* __restrict__ biask,
                const float* __restrict__ biasv,
                unsigned short* __restrict__ Qb, unsigned short* __restrict__ Kb,
                unsigned short* __restrict__ Vb){
  __shared__ unsigned short xt[64*260];
  int b = blockIdx.y;
  int t = threadIdx.x;
  int lane = t&63, w = t>>6, l15 = lane&15, g = lane>>4;

  if (blockIdx.z == 0){
    int y = blockIdx.x;
    float fy = 0.5f*y - 0.25f;
    float y0f = floorf(fy); float wy = fy - y0f;
    int y0 = max(0,min(31,(int)y0f)), y1 = max(0,min(31,(int)y0f+1));
    int x = t & 63, cg = t >> 6;
    float fx = 0.5f*x - 0.25f;
    float x0f = floorf(fx); float wx = fx - x0f;
    int x0 = max(0,min(31,(int)x0f)), x1i = max(0,min(31,(int)x0f+1));
    #pragma unroll 8
    for (int i=0;i<64;i++){
      int c = cg + i*4;
      const float* s0 = x1 + ((size_t)(b*C_ + c)*32 + y0)*32;
      const float* s1 = x1 + ((size_t)(b*C_ + c)*32 + y1)*32;
      float v00=s0[x0], v01=s0[x1i], v10=s1[x0], v11=s1[x1i];
      float v0 = v00 + wx*(v01-v00), v1 = v10 + wx*(v11-v10);
      float val = v0 + wy*(v1-v0);
      xt[x*260 + c] = f2b(val);
    }
    __syncthreads();
    const unsigned short* arow = xt + (w*16+l15)*260 + g*8;
    short8 a[8];
    #pragma unroll
    for (int kk=0;kk<8;kk++){
      short4_ lo = *(const short4_*)(arow + kk*32);
      short4_ hi = *(const short4_*)(arow + kk*32 + 4);
      short8 af;
      af[0]=lo[0];af[1]=lo[1];af[2]=lo[2];af[3]=lo[3];
      af[4]=hi[0];af[5]=hi[1];af[6]=hi[2];af[7]=hi[3];
      a[kk]=af;
    }
    #pragma unroll
    for (int ot=0; ot<2; ot++){
      int o = ot*16 + l15;
      const unsigned short* wrow = wqb + o*C_ + g*8;
      float4v acc = {0.f,0.f,0.f,0.f};
      #pragma unroll
      for (int kk=0;kk<8;kk++){
        short8 bf = *(const short8*)(wrow + kk*32);
        acc = __builtin_amdgcn_mfma_f32_16x16x32_bf16(a[kk], bf, acc, 0,0,0);
      }
      float bs = biasq[o];
      #pragma unroll
      for (int r=0;r<4;r++){
        float yv = acc[r] + bs;
        yv = yv >= 0.f ? yv : 0.1f*yv;
        int m = y*64 + w*16 + g*4 + r;
        Qb[(size_t)(b*N_+m)*32 + o] = f2b(yv);
      }
    }
  } else {
    int n0 = blockIdx.x*64;
    int n = t & 63, cg = t >> 6;
    #pragma unroll 8
    for (int i=0;i<64;i++){
      int c = cg + i*4;
      float v = x2[(size_t)(b*C_ + c)*N_ + n0 + n];
      xt[n*260 + c] = f2b(v);
    }
    __syncthreads();
    const unsigned short* arow = xt + (w*16+l15)*260 + g*8;
    short8 a[8];
    #pragma unroll
    for (int kk=0;kk<8;kk++){
      short4_ lo = *(const short4_*)(arow + kk*32);
      short4_ hi = *(const short4_*)(arow + kk*32 + 4);
      short8 af;
      af[0]=lo[0];af[1]=lo[1];af[2]=lo[2];af[3]=lo[3];
      af[4]=hi[0];af[5]=hi[1];af[6]=hi[2];af[7]=hi[3];
      a[kk]=af;
    }
    if (blockIdx.z == 1){
      #pragma unroll
      for (int ot=0; ot<2; ot++){
        int o = ot*16 + l15;
        const unsigned short* wrow = wkb + o*C_ + g*8;
        float4v acc = {0.f,0.f,0.f,0.f};
        #pragma unroll
        for (int kk=0;kk<8;kk++){
          short8 bf = *(const short8*)(wrow + kk*32);
          acc = __builtin_amdgcn_mfma_f32_16x16x32_bf16(a[kk], bf, acc, 0,0,0);
        }
        float bs = biask[o];
        #pragma unroll
        for (int r=0;r<4;r++){
          float yv = acc[r] + bs;
          yv = yv >= 0.f ? yv : 0.1f*yv;
          int m = n0 + w*16 + g*4 + r;
          Kb[(size_t)(b*N_+m)*32 + o] = f2b(yv);
        }
      }
    }
    int obase = (blockIdx.z == 1) ? 0 : 8;
    #pragma unroll
    for (int ot=0; ot<8; ot++){
      int o = (obase + ot)*16 + l15;
      const unsigned short* wrow = wvb + (size_t)o*C_ + g*8;
      float4v acc = {0.f,0.f,0.f,0.f};
      #pragma unroll
      for (int kk=0;kk<8;kk++){
        short8 bf = *(const short8*)(wrow + kk*32);
        acc = __builtin_amdgcn_mfma_f32_16x16x32_bf16(a[kk], bf, acc, 0,0,0);
      }
      float bs = biasv[o];
      #pragma unroll
      for (int r=0;r<4;r++){
        float yv = acc[r] + bs;
        yv = yv >= 0.f ? yv : 0.1f*yv;
        int m = n0 + w*16 + g*4 + r;
        Vb[(size_t)(b*C_ + o)*N_ + m] = f2b(yv);
      }
    }
  }
}

// ---------------- flash attention partial (4-way n-split, LDS trimmed for 3 blocks/CU) ----------------
// Grid 1024 (XCD-swizzled: 64 mblk x 4 b x 4 ng), 512 threads (8 waves).
// LDS declared 43,424 B -> rounds to 43,520; 3 x 43,520 = 130,560 <= 131,072 (usable pool)
// -> 3 blocks/CU (R19 missed this by one 512B granule at 44,032).
__global__ __launch_bounds__(512, 2)
void attn_kernel(const unsigned short* __restrict__ Qb,
                 const unsigned short* __restrict__ Kb,
                 const unsigned short* __restrict__ Vb,
                 unsigned short* __restrict__ partial,
                 float* __restrict__ statsg){
  // [0,32768): V dbuf (2 x 16384, 64B rows, slot swizzle)
  // [32768,42880): P parity (2 x 5056; tile stride 1264 = 15*80+64, rows 80B/16B-aligned)
  // 42880: flags[2][4] int ; 42912: scl[2][64] f32 ; total 43424
  __shared__ __align__(16) char smem[43424];
  int* flagsB = (int*)(smem + 42880);
  float* sclB = (float*)(smem + 42912);

  int wg = (blockIdx.z*4 + blockIdx.y)*64 + blockIdx.x;
  int id = (wg & 7)*128 + (wg >> 3);           // bijective XCD swizzle (1024 = 8*128)
  int ng = id >> 8, b = (id >> 6) & 3, mblk = id & 63;
  int t = threadIdx.x, lane = t & 63, w = t >> 6;
  int l15 = lane & 15, g = lane >> 4;

  short8 qf{};
  if (w < 4)
    qf = *(const short8*)(Qb + (size_t)(b*N_ + mblk*64 + w*16 + l15)*32 + g*8);

  float4v acc[4][2];   // [mt][ct]: rows m=mt*16+g*4+r, cols c = w*32+ct*16+l15
  #pragma unroll
  for (int mt=0;mt<4;mt++)
    #pragma unroll
    for (int ct=0;ct<2;ct++) acc[mt][ct] = (float4v){0.f,0.f,0.f,0.f};
  float mrow = -1e30f, lrun = 0.f;
  const float4v zero4 = {0.f,0.f,0.f,0.f};

  // V staging: 1024 16B chunks over 512 threads -> 2 each (linear LDS, inv-swz source)
  u32 goff[2]; int loff[2];
  #pragma unroll
  for (int j=0;j<2;j++){
    int i = j*512 + t;
    int c = i >> 2, sp = i & 3;
    int jj = sp ^ (c & 3) ^ ((c >> 2) & 3);
    loff[j] = i*16;
    goff[j] = (u32)(c*(N_*2)) + (u32)(jj << 4);
  }
  const char* Vbyte = (const char*)Vb + (size_t)b*C_*N_*2 + ng*2048;
  const short* kbase = (const short*)Kb + (size_t)(b*N_ + ng*1024 + l15)*32 + g*8;

  auto stageV = [&](int tt, int par){
    const char* src = Vbyte + tt*64;
    #pragma unroll
    for (int j=0;j<2;j++) gload16(src + goff[j], smem + par*16384 + loff[j]);
  };
  auto loadK = [&](short8 (&kf)[2], int tt){
    const short* kp = kbase + (size_t)tt*1024;   // 32 rows x 32 D shorts
    #pragma unroll
    for (int j=0;j<2;j++) kf[j] = *(const short8*)(kp + j*512);
  };

  // QK(tile 32n) + online softmax -> P/flags/scl parity pdst
  auto softmax_step = [&](const short8 (&kf)[2], int pdst){
    float4v s[2];
    #pragma unroll
    for (int j=0;j<2;j++)
      s[j] = __builtin_amdgcn_mfma_f32_16x16x32_bf16(kf[j], qf, zero4, 0, 0, 0);
    float tmax = fmaxf(fmaxf(fmaxf(s[0][0],s[0][1]),fmaxf(s[0][2],s[0][3])),
                       fmaxf(fmaxf(s[1][0],s[1][1]),fmaxf(s[1][2],s[1][3])));
    int trig = __any((tmax > mrow + 8.f) ? 1 : 0) ? 1 : 0;
    if (lane == 0) flagsB[pdst*4 + w] = trig;
    if (trig){
      float tm = fmaxf(tmax, __shfl_xor(tmax, 16));
      tm = fmaxf(tm, __shfl_xor(tm, 32));
      float mnew = fmaxf(mrow, tm);
      float sc = exp2f(mrow - mnew);
      mrow = mnew; lrun *= sc;
      if (lane < 16) sclB[pdst*64 + w*16 + l15] = sc;
    }
    char* pw = smem + 32768 + pdst*5056 + w*1264 + l15*80;
    #pragma unroll
    for (int j=0;j<2;j++){
      float p0 = exp2f(s[j][0]-mrow), p1 = exp2f(s[j][1]-mrow);
      float p2 = exp2f(s[j][2]-mrow), p3 = exp2f(s[j][3]-mrow);
      lrun += (p0+p1)+(p2+p3);
      u32 lo = cvtpk(p0, p1);
      u32 hi = cvtpk(p2, p3);
      *(uint2v*)(pw + j*32 + g*8) = (uint2v){lo, hi};
    }
  };

  auto body = [&](int tt, short8 (&kC)[2], short8 (&kN)[2]){
    int pp = tt & 1, nx = (tt+1) & 1;
    if (tt < 31) stageV(tt+1, nx);
    if (w < 4){
      loadK(kN, (tt+2) & 31);
      if (tt < 31) softmax_step(kC, nx);
    }
    // rescale partials with flags/scl of tile t
    #pragma unroll
    for (int mt=0;mt<4;mt++){
      if (flagsB[pp*4 + mt]){
        float4v sv = *(float4v*)(sclB + pp*64 + mt*16 + g*4);
        #pragma unroll
        for (int ct=0;ct<2;ct++){
          acc[mt][ct][0]*=sv[0]; acc[mt][ct][1]*=sv[1];
          acc[mt][ct][2]*=sv[2]; acc[mt][ct][3]*=sv[3];
        }
      }
    }
    // PV(t): full k=32, c-range w*32
    const char* pb = smem + 32768 + pp*5056;
    const char* vbc = smem + pp*16384;
    short8 pa[4], vf[2];
    #pragma unroll
    for (int mt=0;mt<4;mt++)
      pa[mt] = *(const short8*)(pb + mt*1264 + l15*80 + g*16);
    #pragma unroll
    for (int ct=0;ct<2;ct++){
      int row = w*32 + ct*16 + l15;
      int slot = g ^ (row & 3) ^ ((row >> 2) & 3);
      vf[ct] = *(const short8*)(vbc + row*64 + slot*16);
    }
    __builtin_amdgcn_s_setprio(1);
    #pragma unroll
    for (int mt=0;mt<4;mt++)
      #pragma unroll
      for (int ct=0;ct<2;ct++)
        acc[mt][ct] = __builtin_amdgcn_mfma_f32_16x16x32_bf16(pa[mt], vf[ct], acc[mt][ct], 0, 0, 0);
    __builtin_amdgcn_s_setprio(0);
    __syncthreads();   // drains stage DMA; publishes P(t+1)/flags/scl; V(t) reads done
  };

  // prologue
  short8 kA[2], kB[2];
  stageV(0, 0);
  if (w < 4){
    short8 k0[2];
    loadK(k0, 0);
    softmax_step(k0, 0);
    loadK(kA, 1);
  }
  __syncthreads();

  for (int tt=0; tt<32; tt+=2){
    body(tt,   kA, kB);
    body(tt+1, kB, kA);
  }

  // epilogue: stats + bf16 partial (no normalize; combine merges ng quarters)
  if (w < 4){
    lrun += __shfl_xor(lrun, 16);
    lrun += __shfl_xor(lrun, 32);
    if (lane < 16){
      int sidx = (((b*4+ng)*64 + mblk)*64 + w*16 + l15)*2;
      statsg[sidx] = mrow; statsg[sidx+1] = lrun;
    }
  }
  size_t pbg = (size_t)((b*4+ng)*64 + mblk)*16384;
  #pragma unroll
  for (int mt=0;mt<4;mt++)
    #pragma unroll
    for (int ct=0;ct<2;ct++)
      #pragma unroll
      for (int r=0;r<4;r++){
        int m = mt*16 + g*4 + r;
        int c = w*32 + ct*16 + l15;
        partial[pbg + m*256 + c] = f2b(acc[mt][ct][r]);
      }
}

// ---------------- combine: merge 4 ng quarters + gamma*O/L + inline bilinear residual ----------------
// grid (4 ctile, 64 mblk, 4 b), 256 thr.
__global__ __launch_bounds__(256, 2)
void combine_kernel(const unsigned short* __restrict__ partial,
                    const float* __restrict__ statsg,
                    const float* __restrict__ x1,
                    const float* __restrict__ gamma_p,
                    float* __restrict__ out){
  __shared__ float tile[64][65];
  __shared__ float fbuf[64][5];
  int b = blockIdx.z, mblk = blockIdx.y, ct4 = blockIdx.x;
  int t = threadIdx.x;
  float gm = gamma_p[0];
  if (t < 64){
    float mq[4], lq[4];
    #pragma unroll
    for (int q=0;q<4;q++){
      int s = (((b*4+q)*64 + mblk)*64 + t)*2;
      mq[q] = statsg[s]; lq[q] = statsg[s+1];
    }
    float M = fmaxf(fmaxf(mq[0],mq[1]), fmaxf(mq[2],mq[3]));
    float L = 0.f;
    #pragma unroll
    for (int q=0;q<4;q++){
      float f = exp2f(mq[q] - M);
      fbuf[t][q] = f;
      L += lq[q]*f;
    }
    fbuf[t][4] = gm / L;
  }
  __syncthreads();
  size_t pqb[4];
  #pragma unroll
  for (int q=0;q<4;q++)
    pqb[q] = (size_t)((b*4+q)*64 + mblk)*16384 + ct4*64;
  int c_l = t & 63, mg = t >> 6;
  #pragma unroll 4
  for (int pass=0; pass<16; pass++){
    int m = pass*4 + mg;
    float v = 0.f;
    #pragma unroll
    for (int q=0;q<4;q++)
      v += b2f(partial[pqb[q] + m*256 + c_l]) * fbuf[m][q];
    tile[m][c_l] = v * fbuf[m][4];
  }
  __syncthreads();
  // inline bilinear: y = mblk (uniform), x = m (per lane)
  int y = mblk;
  float fy = 0.5f*y - 0.25f;
  float y0f = floorf(fy); float wy = fy - y0f;
  int y0 = max(0,min(31,(int)y0f)), y1 = max(0,min(31,(int)y0f+1));
  int m = t & 63, cg = t >> 6;
  float fx = 0.5f*m - 0.25f;
  float x0f = floorf(fx); float wx = fx - x0f;
  int x0 = max(0,min(31,(int)x0f)), x1i = max(0,min(31,(int)x0f+1));
  #pragma unroll 4
  for (int pass=0; pass<16; pass++){
    int c_l2 = pass*4 + cg;
    const float* s0 = x1 + ((size_t)(b*C_ + ct4*64 + c_l2)*32 + y0)*32;
    const float* s1 = x1 + ((size_t)(b*C_ + ct4*64 + c_l2)*32 + y1)*32;
    float v00=s0[x0], v01=s0[x1i], v10=s1[x0], v11=s1[x1i];
    float v0 = v00 + wx*(v01-v00), v1 = v10 + wx*(v11-v10);
    float xv = v0 + wy*(v1-v0);
    size_t gidx = ((size_t)(b*C_ + ct4*64 + c_l2))*N_ + mblk*64 + m;
    out[gidx] = tile[m][c_l2] + xv;
  }
}

extern "C" void kernel_launch(void* const* d_in, const int* in_sizes, int n_in,
                              void* d_out, int out_size, void* d_ws, size_t ws_size,
                              hipStream_t stream){
  (void)in_sizes; (void)n_in; (void)out_size; (void)ws_size;
  const float* x1 = (const float*)d_in[0];
  const float* x2 = (const float*)d_in[1];
  const float* wq = (const float*)d_in[2];
  const float* wk = (const float*)d_in[3];
  const float* wv = (const float*)d_in[4];
  const float* gq = (const float*)d_in[5];
  const float* bq = (const float*)d_in[6];
  const float* mq = (const float*)d_in[7];
  const float* vq = (const float*)d_in[8];
  const float* gk = (const float*)d_in[9];
  const float* bk = (const float*)d_in[10];
  const float* mk = (const float*)d_in[11];
  const float* vk = (const float*)d_in[12];
  const float* gv = (const float*)d_in[13];
  const float* bv = (const float*)d_in[14];
  const float* mv = (const float*)d_in[15];
  const float* vv = (const float*)d_in[16];
  const float* gamma = (const float*)d_in[17];
  float* out = (float*)d_out;

  char* p = (char*)d_ws;
  unsigned short* Qb    = (unsigned short*)p; p += (size_t)B_*N_*32*2;      // 1 MB
  unsigned short* Kb    = (unsigned short*)p; p += (size_t)B_*N_*32*2;      // 1 MB
  unsigned short* Vb    = (unsigned short*)p; p += (size_t)B_*C_*N_*2;      // 8 MB
  unsigned short* wqb   = (unsigned short*)p; p += 32*256*2;
  unsigned short* wkb   = (unsigned short*)p; p += 32*256*2;
  unsigned short* wvb   = (unsigned short*)p; p += 256*256*2;
  float* biasq          = (float*)p;          p += 32*4;
  float* biask          = (float*)p;          p += 32*4;
  float* biasv          = (float*)p;          p += 256*4;
  unsigned short* parti = (unsigned short*)p; p += (size_t)1024*16384*2;    // 32 MB
  float* statsg         = (float*)p;          p += (size_t)1024*64*2*4;     // 512 KB

  fold_w_kernel<<<256, 256, 0, stream>>>(wq,wk,wv,gq,bq,mq,vq,gk,bk,mk,vk,gv,bv,mv,vv,
                                         wqb,wkb,wvb,biasq,biask,biasv);
  pre_kernel<<<dim3(64,4,3), 256, 0, stream>>>(x1, x2, wqb, wkb, wvb,
                                               biasq, biask, biasv, Qb, Kb, Vb);
  attn_kernel<<<dim3(64,4,4), 512, 0, stream>>>(Qb, Kb, Vb, parti, statsg);
  combine_kernel<<<dim3(4,64,4), 256, 0, stream>>>(parti, statsg, x1, gamma, out);
}

// Round 22
// 109.795 us; speedup vs baseline: 1.0547x; 1.0547x over previous
//
#include <hip/hip_runtime.h>

#define B_ 4
#define C_ 256
#define N_ 4096
#define LOG2E 1.4426950408889634f

typedef short short8 __attribute__((ext_vector_type(8)));
typedef short short4_ __attribute__((ext_vector_type(4)));
typedef float float4v __attribute__((ext_vector_type(4)));
typedef unsigned int uint2v __attribute__((ext_vector_type(2)));
typedef unsigned int u32;

__device__ inline unsigned short f2b(float x){
  unsigned u = __builtin_bit_cast(unsigned, x);
  u = u + 0x7FFFu + ((u >> 16) & 1u);
  return (unsigned short)(u >> 16);
}
__device__ inline float b2f(unsigned short s){
  return __builtin_bit_cast(float, ((u32)s) << 16);
}
__device__ inline u32 cvtpk(float lo, float hi){
  u32 r; asm("v_cvt_pk_bf16_f32 %0, %1, %2" : "=v"(r) : "v"(lo), "v"(hi)); return r;
}
__device__ inline void gload16(const void* g, void* l){
  __builtin_amdgcn_global_load_lds((const __attribute__((address_space(1))) u32*)g,
                                   (__attribute__((address_space(3))) u32*)l, 16, 0, 0);
}

// ---------------- fold BN into weights (log2e folded into Q path) ----------------
__global__ void fold_w_kernel(const float* __restrict__ wq, const float* __restrict__ wk,
    const float* __restrict__ wv,
    const float* gq, const float* bq, const float* mq, const float* vq,
    const float* gk, const float* bk, const float* mk, const float* vk,
    const float* gv, const float* bv, const float* mv, const float* vv,
    unsigned short* wqb, unsigned short* wkb, unsigned short* wvb,
    float* biasq, float* biask, float* biasv){
  int i = blockIdx.x*256 + threadIdx.x;   // 65536 threads
  int o = i >> 8;
  float sv = gv[o]*rsqrtf(vv[o]+1e-5f);
  wvb[i] = f2b(wv[i]*sv);
  if (i < 32*256){
    int oq = i >> 8;
    float sq = gq[oq]*rsqrtf(vq[oq]+1e-5f);
    wqb[i] = f2b(wq[i]*sq*LOG2E);
    float sk = gk[oq]*rsqrtf(vk[oq]+1e-5f);
    wkb[i] = f2b(wk[i]*sk);
  }
  if (i < 256) biasv[i] = bv[i] - mv[i]*(gv[i]*rsqrtf(vv[i]+1e-5f));
  if (i < 32){
    biasq[i] = (bq[i] - mq[i]*(gq[i]*rsqrtf(vq[i]+1e-5f)))*LOG2E;
    biask[i] = bk[i] - mk[i]*(gk[i]*rsqrtf(vk[i]+1e-5f));
  }
}

// ------- preprocessing: z=0 upsample+Qconv+x1u ; z=1 x2 stage+K+V[0:128) ; z=2 x2 stage+V[128:256) -------
__global__ __launch_bounds__(256, 2)
void pre_kernel(const float* __restrict__ x1, const float* __restrict__ x2,
                const unsigned short* __restrict__ wqb,
                const unsigned short* __restrict__ wkb,
                const unsigned short* __restrict__ wvb,
                const float* __restrict__ biasq, const float* __restrict__ biask,
                const float* __restrict__ biasv,
                float* __restrict__ x1u,
                unsigned short* __restrict__ Qb, unsigned short* __restrict__ Kb,
                unsigned short* __restrict__ Vb){
  __shared__ unsigned short xt[64*260];
  int b = blockIdx.y;
  int t = threadIdx.x;
  int lane = t&63, w = t>>6, l15 = lane&15, g = lane>>4;

  if (blockIdx.z == 0){
    int y = blockIdx.x;
    float fy = 0.5f*y - 0.25f;
    float y0f = floorf(fy); float wy = fy - y0f;
    int y0 = max(0,min(31,(int)y0f)), y1 = max(0,min(31,(int)y0f+1));
    int x = t & 63, cg = t >> 6;
    float fx = 0.5f*x - 0.25f;
    float x0f = floorf(fx); float wx = fx - x0f;
    int x0 = max(0,min(31,(int)x0f)), x1i = max(0,min(31,(int)x0f+1));
    #pragma unroll 8
    for (int i=0;i<64;i++){
      int c = cg + i*4;
      const float* s0 = x1 + ((size_t)(b*C_ + c)*32 + y0)*32;
      const float* s1 = x1 + ((size_t)(b*C_ + c)*32 + y1)*32;
      float v00=s0[x0], v01=s0[x1i], v10=s1[x0], v11=s1[x1i];
      float v0 = v00 + wx*(v01-v00), v1 = v10 + wx*(v11-v10);
      float val = v0 + wy*(v1-v0);
      x1u[(size_t)(b*C_ + c)*N_ + y*64 + x] = val;
      xt[x*260 + c] = f2b(val);
    }
    __syncthreads();
    const unsigned short* arow = xt + (w*16+l15)*260 + g*8;
    short8 a[8];
    #pragma unroll
    for (int kk=0;kk<8;kk++){
      short4_ lo = *(const short4_*)(arow + kk*32);
      short4_ hi = *(const short4_*)(arow + kk*32 + 4);
      short8 af;
      af[0]=lo[0];af[1]=lo[1];af[2]=lo[2];af[3]=lo[3];
      af[4]=hi[0];af[5]=hi[1];af[6]=hi[2];af[7]=hi[3];
      a[kk]=af;
    }
    #pragma unroll
    for (int ot=0; ot<2; ot++){
      int o = ot*16 + l15;
      const unsigned short* wrow = wqb + o*C_ + g*8;
      float4v acc = {0.f,0.f,0.f,0.f};
      #pragma unroll
      for (int kk=0;kk<8;kk++){
        short8 bf = *(const short8*)(wrow + kk*32);
        acc = __builtin_amdgcn_mfma_f32_16x16x32_bf16(a[kk], bf, acc, 0,0,0);
      }
      float bs = biasq[o];
      #pragma unroll
      for (int r=0;r<4;r++){
        float yv = acc[r] + bs;
        yv = yv >= 0.f ? yv : 0.1f*yv;
        int m = y*64 + w*16 + g*4 + r;
        Qb[(size_t)(b*N_+m)*32 + o] = f2b(yv);
      }
    }
  } else {
    int n0 = blockIdx.x*64;
    int n = t & 63, cg = t >> 6;
    #pragma unroll 8
    for (int i=0;i<64;i++){
      int c = cg + i*4;
      float v = x2[(size_t)(b*C_ + c)*N_ + n0 + n];
      xt[n*260 + c] = f2b(v);
    }
    __syncthreads();
    const unsigned short* arow = xt + (w*16+l15)*260 + g*8;
    short8 a[8];
    #pragma unroll
    for (int kk=0;kk<8;kk++){
      short4_ lo = *(const short4_*)(arow + kk*32);
      short4_ hi = *(const short4_*)(arow + kk*32 + 4);
      short8 af;
      af[0]=lo[0];af[1]=lo[1];af[2]=lo[2];af[3]=lo[3];
      af[4]=hi[0];af[5]=hi[1];af[6]=hi[2];af[7]=hi[3];
      a[kk]=af;
    }
    if (blockIdx.z == 1){
      #pragma unroll
      for (int ot=0; ot<2; ot++){
        int o = ot*16 + l15;
        const unsigned short* wrow = wkb + o*C_ + g*8;
        float4v acc = {0.f,0.f,0.f,0.f};
        #pragma unroll
        for (int kk=0;kk<8;kk++){
          short8 bf = *(const short8*)(wrow + kk*32);
          acc = __builtin_amdgcn_mfma_f32_16x16x32_bf16(a[kk], bf, acc, 0,0,0);
        }
        float bs = biask[o];
        #pragma unroll
        for (int r=0;r<4;r++){
          float yv = acc[r] + bs;
          yv = yv >= 0.f ? yv : 0.1f*yv;
          int m = n0 + w*16 + g*4 + r;
          Kb[(size_t)(b*N_+m)*32 + o] = f2b(yv);
        }
      }
    }
    int obase = (blockIdx.z == 1) ? 0 : 8;
    #pragma unroll
    for (int ot=0; ot<8; ot++){
      int o = (obase + ot)*16 + l15;
      const unsigned short* wrow = wvb + (size_t)o*C_ + g*8;
      float4v acc = {0.f,0.f,0.f,0.f};
      #pragma unroll
      for (int kk=0;kk<8;kk++){
        short8 bf = *(const short8*)(wrow + kk*32);
        acc = __builtin_amdgcn_mfma_f32_16x16x32_bf16(a[kk], bf, acc, 0,0,0);
      }
      float bs = biasv[o];
      #pragma unroll
      for (int r=0;r<4;r++){
        float yv = acc[r] + bs;
        yv = yv >= 0.f ? yv : 0.1f*yv;
        int m = n0 + w*16 + g*4 + r;
        Vb[(size_t)(b*C_ + o)*N_ + m] = f2b(yv);
      }
    }
  }
}

// ---------------- flash attention partial (n-split): writes bf16 partial + (m,l) stats ----------------
// Grid 512 (XCD-swizzled: 64 mblk x 4 b x 2 ng), 512 threads (8 waves), 2 blocks/CU.
// Block: M=64 rows (mblk), n in [ng*2048, +2048), KVBLK=32 -> 64 iters, 1 barrier/iter.
// LDS 43.5 KB. Waves 0-3: softmax of 16-row tile w (pipelined 1 tile ahead). All 8 waves:
// PV c-split (w*32, 32 channels), full k=32. acc[4mt][2ct].  [R15/R20 proven: 72.4-72.6 us]
__global__ __launch_bounds__(512, 2)
void attn_kernel(const unsigned short* __restrict__ Qb,
                 const unsigned short* __restrict__ Kb,
                 const unsigned short* __restrict__ Vb,
                 unsigned short* __restrict__ partial,
                 float* __restrict__ statsg){
  // [0,32768): V dbuf (2 x 16384, 64B rows, slot^(c&3) swizzle)
  // [32768,43008): P parity (2 x 4 tiles x 16 rows x 80B)
  // 43008: flags[2][4] int ; 43040: scl[2][64] f32
  __shared__ __align__(16) char smem[43552];
  int* flagsB = (int*)(smem + 43008);
  float* sclB = (float*)(smem + 43040);

  int wg = (blockIdx.z*4 + blockIdx.y)*64 + blockIdx.x;
  int id = (wg & 7)*64 + (wg >> 3);            // bijective XCD swizzle (512 = 8*64)
  int ng = id >> 8, b = (id >> 6) & 3, mblk = id & 63;
  int t = threadIdx.x, lane = t & 63, w = t >> 6;
  int l15 = lane & 15, g = lane >> 4;

  short8 qf{};
  if (w < 4)
    qf = *(const short8*)(Qb + (size_t)(b*N_ + mblk*64 + w*16 + l15)*32 + g*8);

  float4v acc[4][2];   // [mt][ct]: rows m=mt*16+g*4+r, cols c = w*32+ct*16+l15
  #pragma unroll
  for (int mt=0;mt<4;mt++)
    #pragma unroll
    for (int ct=0;ct<2;ct++) acc[mt][ct] = (float4v){0.f,0.f,0.f,0.f};
  float mrow = -1e30f, lrun = 0.f;
  const float4v zero4 = {0.f,0.f,0.f,0.f};

  // V staging: 1024 16B chunks over 512 threads -> 2 each (linear LDS, inv-swz source)
  u32 goff[2]; int loff[2];
  #pragma unroll
  for (int j=0;j<2;j++){
    int i = j*512 + t;
    int c = i >> 2, jj = i & 3;
    loff[j] = i*16;
    goff[j] = (u32)(c*(N_*2)) + (u32)((jj ^ (c & 3)) << 4);
  }
  const char* Vbyte = (const char*)Vb + (size_t)b*C_*N_*2 + ng*4096;
  const short* kbase = (const short*)Kb + (size_t)(b*N_ + ng*2048 + l15)*32 + g*8;

  auto stageV = [&](int tt, int par){
    const char* src = Vbyte + tt*64;
    #pragma unroll
    for (int j=0;j<2;j++) gload16(src + goff[j], smem + par*16384 + loff[j]);
  };
  auto loadK = [&](short8 (&kf)[2], int tt){
    const short* kp = kbase + (size_t)tt*1024;   // 32 rows x 32 D shorts
    #pragma unroll
    for (int j=0;j<2;j++) kf[j] = *(const short8*)(kp + j*512);
  };

  // QK(tile 32n) + online softmax -> P/flags/scl parity pdst
  auto softmax_step = [&](const short8 (&kf)[2], int pdst){
    float4v s[2];
    #pragma unroll
    for (int j=0;j<2;j++)
      s[j] = __builtin_amdgcn_mfma_f32_16x16x32_bf16(kf[j], qf, zero4, 0, 0, 0);
    float tmax = fmaxf(fmaxf(fmaxf(s[0][0],s[0][1]),fmaxf(s[0][2],s[0][3])),
                       fmaxf(fmaxf(s[1][0],s[1][1]),fmaxf(s[1][2],s[1][3])));
    int trig = __any((tmax > mrow + 8.f) ? 1 : 0) ? 1 : 0;
    if (lane == 0) flagsB[pdst*4 + w] = trig;
    if (trig){
      float tm = fmaxf(tmax, __shfl_xor(tmax, 16));
      tm = fmaxf(tm, __shfl_xor(tm, 32));
      float mnew = fmaxf(mrow, tm);
      float sc = exp2f(mrow - mnew);
      mrow = mnew; lrun *= sc;
      if (lane < 16) sclB[pdst*64 + w*16 + l15] = sc;
    }
    char* pw = smem + 32768 + pdst*5120 + w*1280 + l15*80;
    #pragma unroll
    for (int j=0;j<2;j++){
      float p0 = exp2f(s[j][0]-mrow), p1 = exp2f(s[j][1]-mrow);
      float p2 = exp2f(s[j][2]-mrow), p3 = exp2f(s[j][3]-mrow);
      lrun += (p0+p1)+(p2+p3);
      u32 lo = cvtpk(p0, p1);
      u32 hi = cvtpk(p2, p3);
      *(uint2v*)(pw + j*32 + g*8) = (uint2v){lo, hi};
    }
  };

  auto body = [&](int tt, short8 (&kC)[2], short8 (&kN)[2]){
    int pp = tt & 1, nx = (tt+1) & 1;
    if (tt < 63) stageV(tt+1, nx);
    if (w < 4){
      loadK(kN, (tt+2) & 63);
      if (tt < 63) softmax_step(kC, nx);
    }
    // rescale partials with flags/scl of tile t
    #pragma unroll
    for (int mt=0;mt<4;mt++){
      if (flagsB[pp*4 + mt]){
        float4v sv = *(float4v*)(sclB + pp*64 + mt*16 + g*4);
        #pragma unroll
        for (int ct=0;ct<2;ct++){
          acc[mt][ct][0]*=sv[0]; acc[mt][ct][1]*=sv[1];
          acc[mt][ct][2]*=sv[2]; acc[mt][ct][3]*=sv[3];
        }
      }
    }
    // PV(t): full k=32, c-range w*32
    const char* pb = smem + 32768 + pp*5120;
    const char* vbc = smem + pp*16384;
    short8 pa[4], vf[2];
    #pragma unroll
    for (int mt=0;mt<4;mt++)
      pa[mt] = *(const short8*)(pb + mt*1280 + l15*80 + g*16);
    #pragma unroll
    for (int ct=0;ct<2;ct++){
      int row = w*32 + ct*16 + l15;
      vf[ct] = *(const short8*)(vbc + row*64 + ((g*16) ^ ((row & 3) << 4)));
    }
    __builtin_amdgcn_s_setprio(1);
    #pragma unroll
    for (int mt=0;mt<4;mt++)
      #pragma unroll
      for (int ct=0;ct<2;ct++)
        acc[mt][ct] = __builtin_amdgcn_mfma_f32_16x16x32_bf16(pa[mt], vf[ct], acc[mt][ct], 0, 0, 0);
    __builtin_amdgcn_s_setprio(0);
    __syncthreads();   // drains stage DMA; publishes P(t+1)/flags/scl; V(t) reads done
  };

  // prologue
  short8 kA[2], kB[2];
  stageV(0, 0);
  if (w < 4){
    short8 k0[2];
    loadK(k0, 0);
    softmax_step(k0, 0);
    loadK(kA, 1);
  }
  __syncthreads();

  for (int tt=0; tt<64; tt+=2){
    body(tt,   kA, kB);
    body(tt+1, kB, kA);
  }

  // epilogue: stats + bf16 partial (no normalize; combine kernel merges ng halves)
  if (w < 4){
    lrun += __shfl_xor(lrun, 16);
    lrun += __shfl_xor(lrun, 32);
    if (lane < 16){
      int sidx = (((b*2+ng)*64 + mblk)*64 + w*16 + l15)*2;
      statsg[sidx] = mrow; statsg[sidx+1] = lrun;
    }
  }
  size_t pbg = (size_t)((b*2+ng)*64 + mblk)*16384;
  #pragma unroll
  for (int mt=0;mt<4;mt++)
    #pragma unroll
    for (int ct=0;ct<2;ct++)
      #pragma unroll
      for (int r=0;r<4;r++){
        int m = mt*16 + g*4 + r;
        int c = w*32 + ct*16 + l15;
        partial[pbg + m*256 + c] = f2b(acc[mt][ct][r]);
      }
}

// ---------------- combine: merge ng halves (softmax merge) + gamma*O/L + x1u ----------------
// grid (4 ctile, 64 mblk, 4 b), 256 thr. Transposes [m][c] partials to [c][m] output via LDS.
__global__ __launch_bounds__(256, 2)
void combine_kernel(const unsigned short* __restrict__ partial,
                    const float* __restrict__ statsg,
                    const float* __restrict__ x1u,
                    const float* __restrict__ gamma_p,
                    float* __restrict__ out){
  __shared__ float tile[64][65];
  __shared__ float fbuf[64][3];
  int b = blockIdx.z, mblk = blockIdx.y, ct4 = blockIdx.x;
  int t = threadIdx.x;
  float gm = gamma_p[0];
  if (t < 64){
    int s0 = (((b*2+0)*64 + mblk)*64 + t)*2;
    int s1 = (((b*2+1)*64 + mblk)*64 + t)*2;
    float m0 = statsg[s0], l0 = statsg[s0+1];
    float m1 = statsg[s1], l1 = statsg[s1+1];
    float M = fmaxf(m0, m1);
    float f0 = exp2f(m0 - M), f1 = exp2f(m1 - M);
    float L = l0*f0 + l1*f1;
    fbuf[t][0] = f0; fbuf[t][1] = f1; fbuf[t][2] = gm / L;
  }
  __syncthreads();
  size_t p0b = (size_t)((b*2+0)*64 + mblk)*16384 + ct4*64;
  size_t p1b = (size_t)((b*2+1)*64 + mblk)*16384 + ct4*64;
  int c_l = t & 63, mg = t >> 6;
  #pragma unroll 4
  for (int pass=0; pass<16; pass++){
    int m = pass*4 + mg;
    float v0 = b2f(partial[p0b + m*256 + c_l]);
    float v1 = b2f(partial[p1b + m*256 + c_l]);
    tile[m][c_l] = (v0*fbuf[m][0] + v1*fbuf[m][1]) * fbuf[m][2];
  }
  __syncthreads();
  int m = t & 63, cg = t >> 6;
  #pragma unroll 4
  for (int pass=0; pass<16; pass++){
    int c_l2 = pass*4 + cg;
    size_t gidx = ((size_t)(b*C_ + ct4*64 + c_l2))*N_ + mblk*64 + m;
    out[gidx] = tile[m][c_l2] + x1u[gidx];
  }
}

extern "C" void kernel_launch(void* const* d_in, const int* in_sizes, int n_in,
                              void* d_out, int out_size, void* d_ws, size_t ws_size,
                              hipStream_t stream){
  (void)in_sizes; (void)n_in; (void)out_size; (void)ws_size;
  const float* x1 = (const float*)d_in[0];
  const float* x2 = (const float*)d_in[1];
  const float* wq = (const float*)d_in[2];
  const float* wk = (const float*)d_in[3];
  const float* wv = (const float*)d_in[4];
  const float* gq = (const float*)d_in[5];
  const float* bq = (const float*)d_in[6];
  const float* mq = (const float*)d_in[7];
  const float* vq = (const float*)d_in[8];
  const float* gk = (const float*)d_in[9];
  const float* bk = (const float*)d_in[10];
  const float* mk = (const float*)d_in[11];
  const float* vk = (const float*)d_in[12];
  const float* gv = (const float*)d_in[13];
  const float* bv = (const float*)d_in[14];
  const float* mv = (const float*)d_in[15];
  const float* vv = (const float*)d_in[16];
  const float* gamma = (const float*)d_in[17];
  float* out = (float*)d_out;

  char* p = (char*)d_ws;
  float* x1u            = (float*)p;          p += (size_t)B_*C_*N_*4;      // 16 MB
  unsigned short* Qb    = (unsigned short*)p; p += (size_t)B_*N_*32*2;      // 1 MB
  unsigned short* Kb    = (unsigned short*)p; p += (size_t)B_*N_*32*2;      // 1 MB
  unsigned short* Vb    = (unsigned short*)p; p += (size_t)B_*C_*N_*2;      // 8 MB
  unsigned short* wqb   = (unsigned short*)p; p += 32*256*2;
  unsigned short* wkb   = (unsigned short*)p; p += 32*256*2;
  unsigned short* wvb   = (unsigned short*)p; p += 256*256*2;
  float* biasq          = (float*)p;          p += 32*4;
  float* biask          = (float*)p;          p += 32*4;
  float* biasv          = (float*)p;          p += 256*4;
  unsigned short* parti = (unsigned short*)p; p += (size_t)512*16384*2;     // 16 MB
  float* statsg         = (float*)p;          p += (size_t)512*64*2*4;      // 256 KB

  fold_w_kernel<<<256, 256, 0, stream>>>(wq,wk,wv,gq,bq,mq,vq,gk,bk,mk,vk,gv,bv,mv,vv,
                                         wqb,wkb,wvb,biasq,biask,biasv);
  pre_kernel<<<dim3(64,4,3), 256, 0, stream>>>(x1, x2, wqb, wkb, wvb,
                                               biasq, biask, biasv, x1u, Qb, Kb, Vb);
  attn_kernel<<<dim3(64,4,2), 512, 0, stream>>>(Qb, Kb, Vb, parti, statsg);
  combine_kernel<<<dim3(4,64,4), 256, 0, stream>>>(parti, statsg, x1u, gamma, out);
}

// Round 23
// 109.401 us; speedup vs baseline: 1.0585x; 1.0036x over previous
//
#include <hip/hip_runtime.h>

#define B_ 4
#define C_ 256
#define N_ 4096
#define LOG2E 1.4426950408889634f

typedef short short8 __attribute__((ext_vector_type(8)));
typedef short short4_ __attribute__((ext_vector_type(4)));
typedef float float4v __attribute__((ext_vector_type(4)));
typedef unsigned int uint2v __attribute__((ext_vector_type(2)));
typedef unsigned int u32;

__device__ inline unsigned short f2b(float x){
  unsigned u = __builtin_bit_cast(unsigned, x);
  u = u + 0x7FFFu + ((u >> 16) & 1u);
  return (unsigned short)(u >> 16);
}
__device__ inline float b2f(unsigned short s){
  return __builtin_bit_cast(float, ((u32)s) << 16);
}
__device__ inline u32 cvtpk(float lo, float hi){
  u32 r; asm("v_cvt_pk_bf16_f32 %0, %1, %2" : "=v"(r) : "v"(lo), "v"(hi)); return r;
}
__device__ inline void gload16(const void* g, void* l){
  __builtin_amdgcn_global_load_lds((const __attribute__((address_space(1))) u32*)g,
                                   (__attribute__((address_space(3))) u32*)l, 16, 0, 0);
}

// ---------------- fold BN into weights (log2e folded into Q path) ----------------
__global__ void fold_w_kernel(const float* __restrict__ wq, const float* __restrict__ wk,
    const float* __restrict__ wv,
    const float* gq, const float* bq, const float* mq, const float* vq,
    const float* gk, const float* bk, const float* mk, const float* vk,
    const float* gv, const float* bv, const float* mv, const float* vv,
    unsigned short* wqb, unsigned short* wkb, unsigned short* wvb,
    float* biasq, float* biask, float* biasv){
  int i = blockIdx.x*256 + threadIdx.x;   // 65536 threads
  int o = i >> 8;
  float sv = gv[o]*rsqrtf(vv[o]+1e-5f);
  wvb[i] = f2b(wv[i]*sv);
  if (i < 32*256){
    int oq = i >> 8;
    float sq = gq[oq]*rsqrtf(vq[oq]+1e-5f);
    wqb[i] = f2b(wq[i]*sq*LOG2E);
    float sk = gk[oq]*rsqrtf(vk[oq]+1e-5f);
    wkb[i] = f2b(wk[i]*sk);
  }
  if (i < 256) biasv[i] = bv[i] - mv[i]*(gv[i]*rsqrtf(vv[i]+1e-5f));
  if (i < 32){
    biasq[i] = (bq[i] - mq[i]*(gq[i]*rsqrtf(vq[i]+1e-5f)))*LOG2E;
    biask[i] = bk[i] - mk[i]*(gk[i]*rsqrtf(vk[i]+1e-5f));
  }
}

// ------- preprocessing: z=0 upsample+Qconv+x1u ; z=1 x2 stage+K+V[0:128) ; z=2 x2 stage+V[128:256) -------
__global__ __launch_bounds__(256, 2)
void pre_kernel(const float* __restrict__ x1, const float* __restrict__ x2,
                const unsigned short* __restrict__ wqb,
                const unsigned short* __restrict__ wkb,
                const unsigned short* __restrict__ wvb,
                const float* __restrict__ biasq, const float* __restrict__ biask,
                const float* __restrict__ biasv,
                float* __restrict__ x1u,
                unsigned short* __restrict__ Qb, unsigned short* __restrict__ Kb,
                unsigned short* __restrict__ Vb){
  __shared__ unsigned short xt[64*260];
  int b = blockIdx.y;
  int t = threadIdx.x;
  int lane = t&63, w = t>>6, l15 = lane&15, g = lane>>4;

  if (blockIdx.z == 0){
    int y = blockIdx.x;
    float fy = 0.5f*y - 0.25f;
    float y0f = floorf(fy); float wy = fy - y0f;
    int y0 = max(0,min(31,(int)y0f)), y1 = max(0,min(31,(int)y0f+1));
    int x = t & 63, cg = t >> 6;
    float fx = 0.5f*x - 0.25f;
    float x0f = floorf(fx); float wx = fx - x0f;
    int x0 = max(0,min(31,(int)x0f)), x1i = max(0,min(31,(int)x0f+1));
    #pragma unroll 8
    for (int i=0;i<64;i++){
      int c = cg + i*4;
      const float* s0 = x1 + ((size_t)(b*C_ + c)*32 + y0)*32;
      const float* s1 = x1 + ((size_t)(b*C_ + c)*32 + y1)*32;
      float v00=s0[x0], v01=s0[x1i], v10=s1[x0], v11=s1[x1i];
      float v0 = v00 + wx*(v01-v00), v1 = v10 + wx*(v11-v10);
      float val = v0 + wy*(v1-v0);
      x1u[(size_t)(b*C_ + c)*N_ + y*64 + x] = val;
      xt[x*260 + c] = f2b(val);
    }
    __syncthreads();
    const unsigned short* arow = xt + (w*16+l15)*260 + g*8;
    short8 a[8];
    #pragma unroll
    for (int kk=0;kk<8;kk++){
      short4_ lo = *(const short4_*)(arow + kk*32);
      short4_ hi = *(const short4_*)(arow + kk*32 + 4);
      short8 af;
      af[0]=lo[0];af[1]=lo[1];af[2]=lo[2];af[3]=lo[3];
      af[4]=hi[0];af[5]=hi[1];af[6]=hi[2];af[7]=hi[3];
      a[kk]=af;
    }
    #pragma unroll
    for (int ot=0; ot<2; ot++){
      int o = ot*16 + l15;
      const unsigned short* wrow = wqb + o*C_ + g*8;
      float4v acc = {0.f,0.f,0.f,0.f};
      #pragma unroll
      for (int kk=0;kk<8;kk++){
        short8 bf = *(const short8*)(wrow + kk*32);
        acc = __builtin_amdgcn_mfma_f32_16x16x32_bf16(a[kk], bf, acc, 0,0,0);
      }
      float bs = biasq[o];
      #pragma unroll
      for (int r=0;r<4;r++){
        float yv = acc[r] + bs;
        yv = yv >= 0.f ? yv : 0.1f*yv;
        int m = y*64 + w*16 + g*4 + r;
        Qb[(size_t)(b*N_+m)*32 + o] = f2b(yv);
      }
    }
  } else {
    int n0 = blockIdx.x*64;
    int n = t & 63, cg = t >> 6;
    #pragma unroll 8
    for (int i=0;i<64;i++){
      int c = cg + i*4;
      float v = x2[(size_t)(b*C_ + c)*N_ + n0 + n];
      xt[n*260 + c] = f2b(v);
    }
    __syncthreads();
    const unsigned short* arow = xt + (w*16+l15)*260 + g*8;
    short8 a[8];
    #pragma unroll
    for (int kk=0;kk<8;kk++){
      short4_ lo = *(const short4_*)(arow + kk*32);
      short4_ hi = *(const short4_*)(arow + kk*32 + 4);
      short8 af;
      af[0]=lo[0];af[1]=lo[1];af[2]=lo[2];af[3]=lo[3];
      af[4]=hi[0];af[5]=hi[1];af[6]=hi[2];af[7]=hi[3];
      a[kk]=af;
    }
    if (blockIdx.z == 1){
      #pragma unroll
      for (int ot=0; ot<2; ot++){
        int o = ot*16 + l15;
        const unsigned short* wrow = wkb + o*C_ + g*8;
        float4v acc = {0.f,0.f,0.f,0.f};
        #pragma unroll
        for (int kk=0;kk<8;kk++){
          short8 bf = *(const short8*)(wrow + kk*32);
          acc = __builtin_amdgcn_mfma_f32_16x16x32_bf16(a[kk], bf, acc, 0,0,0);
        }
        float bs = biask[o];
        #pragma unroll
        for (int r=0;r<4;r++){
          float yv = acc[r] + bs;
          yv = yv >= 0.f ? yv : 0.1f*yv;
          int m = n0 + w*16 + g*4 + r;
          Kb[(size_t)(b*N_+m)*32 + o] = f2b(yv);
        }
      }
    }
    int obase = (blockIdx.z == 1) ? 0 : 8;
    #pragma unroll
    for (int ot=0; ot<8; ot++){
      int o = (obase + ot)*16 + l15;
      const unsigned short* wrow = wvb + (size_t)o*C_ + g*8;
      float4v acc = {0.f,0.f,0.f,0.f};
      #pragma unroll
      for (int kk=0;kk<8;kk++){
        short8 bf = *(const short8*)(wrow + kk*32);
        acc = __builtin_amdgcn_mfma_f32_16x16x32_bf16(a[kk], bf, acc, 0,0,0);
      }
      float bs = biasv[o];
      #pragma unroll
      for (int r=0;r<4;r++){
        float yv = acc[r] + bs;
        yv = yv >= 0.f ? yv : 0.1f*yv;
        int m = n0 + w*16 + g*4 + r;
        Vb[(size_t)(b*C_ + o)*N_ + m] = f2b(yv);
      }
    }
  }
}

// ---------------- flash attention partial (n-split): writes bf16 partial + (m,l) stats ----------------
// Grid 512 (XCD-swizzled: 64 mblk x 4 b x 2 ng), 512 threads (8 waves), 2 blocks/CU.
// Block: M=64 rows (mblk), n in [ng*2048, +2048), KVBLK=32 -> 64 iters, 1 barrier/iter.
// LDS 43.5 KB. Waves 0-3: softmax of 16-row tile w (pipelined 1 tile ahead). All 8 waves:
// PV c-split (w*32, 32 channels), full k=32. acc[4mt][2ct].  [proven optimum: 72.4-72.8 us]
__global__ __launch_bounds__(512, 2)
void attn_kernel(const unsigned short* __restrict__ Qb,
                 const unsigned short* __restrict__ Kb,
                 const unsigned short* __restrict__ Vb,
                 unsigned short* __restrict__ partial,
                 float* __restrict__ statsg){
  // [0,32768): V dbuf (2 x 16384, 64B rows, slot^(c&3) swizzle)
  // [32768,43008): P parity (2 x 4 tiles x 16 rows x 80B)
  // 43008: flags[2][4] int ; 43040: scl[2][64] f32
  __shared__ __align__(16) char smem[43552];
  int* flagsB = (int*)(smem + 43008);
  float* sclB = (float*)(smem + 43040);

  int wg = (blockIdx.z*4 + blockIdx.y)*64 + blockIdx.x;
  int id = (wg & 7)*64 + (wg >> 3);            // bijective XCD swizzle (512 = 8*64)
  int ng = id >> 8, b = (id >> 6) & 3, mblk = id & 63;
  int t = threadIdx.x, lane = t & 63, w = t >> 6;
  int l15 = lane & 15, g = lane >> 4;

  short8 qf{};
  if (w < 4)
    qf = *(const short8*)(Qb + (size_t)(b*N_ + mblk*64 + w*16 + l15)*32 + g*8);

  float4v acc[4][2];   // [mt][ct]: rows m=mt*16+g*4+r, cols c = w*32+ct*16+l15
  #pragma unroll
  for (int mt=0;mt<4;mt++)
    #pragma unroll
    for (int ct=0;ct<2;ct++) acc[mt][ct] = (float4v){0.f,0.f,0.f,0.f};
  float mrow = -1e30f, lrun = 0.f;
  const float4v zero4 = {0.f,0.f,0.f,0.f};

  // V staging: 1024 16B chunks over 512 threads -> 2 each (linear LDS, inv-swz source)
  u32 goff[2]; int loff[2];
  #pragma unroll
  for (int j=0;j<2;j++){
    int i = j*512 + t;
    int c = i >> 2, jj = i & 3;
    loff[j] = i*16;
    goff[j] = (u32)(c*(N_*2)) + (u32)((jj ^ (c & 3)) << 4);
  }
  const char* Vbyte = (const char*)Vb + (size_t)b*C_*N_*2 + ng*4096;
  const short* kbase = (const short*)Kb + (size_t)(b*N_ + ng*2048 + l15)*32 + g*8;

  auto stageV = [&](int tt, int par){
    const char* src = Vbyte + tt*64;
    #pragma unroll
    for (int j=0;j<2;j++) gload16(src + goff[j], smem + par*16384 + loff[j]);
  };
  auto loadK = [&](short8 (&kf)[2], int tt){
    const short* kp = kbase + (size_t)tt*1024;   // 32 rows x 32 D shorts
    #pragma unroll
    for (int j=0;j<2;j++) kf[j] = *(const short8*)(kp + j*512);
  };

  // QK(tile 32n) + online softmax -> P/flags/scl parity pdst
  auto softmax_step = [&](const short8 (&kf)[2], int pdst){
    float4v s[2];
    #pragma unroll
    for (int j=0;j<2;j++)
      s[j] = __builtin_amdgcn_mfma_f32_16x16x32_bf16(kf[j], qf, zero4, 0, 0, 0);
    float tmax = fmaxf(fmaxf(fmaxf(s[0][0],s[0][1]),fmaxf(s[0][2],s[0][3])),
                       fmaxf(fmaxf(s[1][0],s[1][1]),fmaxf(s[1][2],s[1][3])));
    int trig = __any((tmax > mrow + 8.f) ? 1 : 0) ? 1 : 0;
    if (lane == 0) flagsB[pdst*4 + w] = trig;
    if (trig){
      float tm = fmaxf(tmax, __shfl_xor(tmax, 16));
      tm = fmaxf(tm, __shfl_xor(tm, 32));
      float mnew = fmaxf(mrow, tm);
      float sc = exp2f(mrow - mnew);
      mrow = mnew; lrun *= sc;
      if (lane < 16) sclB[pdst*64 + w*16 + l15] = sc;
    }
    char* pw = smem + 32768 + pdst*5120 + w*1280 + l15*80;
    #pragma unroll
    for (int j=0;j<2;j++){
      float p0 = exp2f(s[j][0]-mrow), p1 = exp2f(s[j][1]-mrow);
      float p2 = exp2f(s[j][2]-mrow), p3 = exp2f(s[j][3]-mrow);
      lrun += (p0+p1)+(p2+p3);
      u32 lo = cvtpk(p0, p1);
      u32 hi = cvtpk(p2, p3);
      *(uint2v*)(pw + j*32 + g*8) = (uint2v){lo, hi};
    }
  };

  auto body = [&](int tt, short8 (&kC)[2], short8 (&kN)[2]){
    int pp = tt & 1, nx = (tt+1) & 1;
    if (tt < 63) stageV(tt+1, nx);
    if (w < 4){
      loadK(kN, (tt+2) & 63);
      if (tt < 63) softmax_step(kC, nx);
    }
    // rescale partials with flags/scl of tile t
    #pragma unroll
    for (int mt=0;mt<4;mt++){
      if (flagsB[pp*4 + mt]){
        float4v sv = *(float4v*)(sclB + pp*64 + mt*16 + g*4);
        #pragma unroll
        for (int ct=0;ct<2;ct++){
          acc[mt][ct][0]*=sv[0]; acc[mt][ct][1]*=sv[1];
          acc[mt][ct][2]*=sv[2]; acc[mt][ct][3]*=sv[3];
        }
      }
    }
    // PV(t): full k=32, c-range w*32
    const char* pb = smem + 32768 + pp*5120;
    const char* vbc = smem + pp*16384;
    short8 pa[4], vf[2];
    #pragma unroll
    for (int mt=0;mt<4;mt++)
      pa[mt] = *(const short8*)(pb + mt*1280 + l15*80 + g*16);
    #pragma unroll
    for (int ct=0;ct<2;ct++){
      int row = w*32 + ct*16 + l15;
      vf[ct] = *(const short8*)(vbc + row*64 + ((g*16) ^ ((row & 3) << 4)));
    }
    __builtin_amdgcn_s_setprio(1);
    #pragma unroll
    for (int mt=0;mt<4;mt++)
      #pragma unroll
      for (int ct=0;ct<2;ct++)
        acc[mt][ct] = __builtin_amdgcn_mfma_f32_16x16x32_bf16(pa[mt], vf[ct], acc[mt][ct], 0, 0, 0);
    __builtin_amdgcn_s_setprio(0);
    __syncthreads();   // drains stage DMA; publishes P(t+1)/flags/scl; V(t) reads done
  };

  // prologue
  short8 kA[2], kB[2];
  stageV(0, 0);
  if (w < 4){
    short8 k0[2];
    loadK(k0, 0);
    softmax_step(k0, 0);
    loadK(kA, 1);
  }
  __syncthreads();

  for (int tt=0; tt<64; tt+=2){
    body(tt,   kA, kB);
    body(tt+1, kB, kA);
  }

  // epilogue: stats + bf16 partial (no normalize; combine kernel merges ng halves)
  if (w < 4){
    lrun += __shfl_xor(lrun, 16);
    lrun += __shfl_xor(lrun, 32);
    if (lane < 16){
      int sidx = (((b*2+ng)*64 + mblk)*64 + w*16 + l15)*2;
      statsg[sidx] = mrow; statsg[sidx+1] = lrun;
    }
  }
  size_t pbg = (size_t)((b*2+ng)*64 + mblk)*16384;
  #pragma unroll
  for (int mt=0;mt<4;mt++)
    #pragma unroll
    for (int ct=0;ct<2;ct++)
      #pragma unroll
      for (int r=0;r<4;r++){
        int m = mt*16 + g*4 + r;
        int c = w*32 + ct*16 + l15;
        partial[pbg + m*256 + c] = f2b(acc[mt][ct][r]);
      }
}

// ---------------- combine: merge ng halves (softmax merge) + gamma*O/L + x1u ----------------
// grid (4 ctile, 64 mblk, 4 b), 256 thr. Transposes [m][c] partials to [c][m] output via LDS.
__global__ __launch_bounds__(256, 2)
void combine_kernel(const unsigned short* __restrict__ partial,
                    const float* __restrict__ statsg,
                    const float* __restrict__ x1u,
                    const float* __restrict__ gamma_p,
                    float* __restrict__ out){
  __shared__ float tile[64][65];
  __shared__ float fbuf[64][3];
  int b = blockIdx.z, mblk = blockIdx.y, ct4 = blockIdx.x;
  int t = threadIdx.x;
  float gm = gamma_p[0];
  if (t < 64){
    int s0 = (((b*2+0)*64 + mblk)*64 + t)*2;
    int s1 = (((b*2+1)*64 + mblk)*64 + t)*2;
    float m0 = statsg[s0], l0 = statsg[s0+1];
    float m1 = statsg[s1], l1 = statsg[s1+1];
    float M = fmaxf(m0, m1);
    float f0 = exp2f(m0 - M), f1 = exp2f(m1 - M);
    float L = l0*f0 + l1*f1;
    fbuf[t][0] = f0; fbuf[t][1] = f1; fbuf[t][2] = gm / L;
  }
  __syncthreads();
  size_t p0b = (size_t)((b*2+0)*64 + mblk)*16384 + ct4*64;
  size_t p1b = (size_t)((b*2+1)*64 + mblk)*16384 + ct4*64;
  int c_l = t & 63, mg = t >> 6;
  #pragma unroll 4
  for (int pass=0; pass<16; pass++){
    int m = pass*4 + mg;
    float v0 = b2f(partial[p0b + m*256 + c_l]);
    float v1 = b2f(partial[p1b + m*256 + c_l]);
    tile[m][c_l] = (v0*fbuf[m][0] + v1*fbuf[m][1]) * fbuf[m][2];
  }
  __syncthreads();
  int m = t & 63, cg = t >> 6;
  #pragma unroll 4
  for (int pass=0; pass<16; pass++){
    int c_l2 = pass*4 + cg;
    size_t gidx = ((size_t)(b*C_ + ct4*64 + c_l2))*N_ + mblk*64 + m;
    out[gidx] = tile[m][c_l2] + x1u[gidx];
  }
}

extern "C" void kernel_launch(void* const* d_in, const int* in_sizes, int n_in,
                              void* d_out, int out_size, void* d_ws, size_t ws_size,
                              hipStream_t stream){
  (void)in_sizes; (void)n_in; (void)out_size; (void)ws_size;
  const float* x1 = (const float*)d_in[0];
  const float* x2 = (const float*)d_in[1];
  const float* wq = (const float*)d_in[2];
  const float* wk = (const float*)d_in[3];
  const float* wv = (const float*)d_in[4];
  const float* gq = (const float*)d_in[5];
  const float* bq = (const float*)d_in[6];
  const float* mq = (const float*)d_in[7];
  const float* vq = (const float*)d_in[8];
  const float* gk = (const float*)d_in[9];
  const float* bk = (const float*)d_in[10];
  const float* mk = (const float*)d_in[11];
  const float* vk = (const float*)d_in[12];
  const float* gv = (const float*)d_in[13];
  const float* bv = (const float*)d_in[14];
  const float* mv = (const float*)d_in[15];
  const float* vv = (const float*)d_in[16];
  const float* gamma = (const float*)d_in[17];
  float* out = (float*)d_out;

  char* p = (char*)d_ws;
  float* x1u            = (float*)p;          p += (size_t)B_*C_*N_*4;      // 16 MB
  unsigned short* Qb    = (unsigned short*)p; p += (size_t)B_*N_*32*2;      // 1 MB
  unsigned short* Kb    = (unsigned short*)p; p += (size_t)B_*N_*32*2;      // 1 MB
  unsigned short* Vb    = (unsigned short*)p; p += (size_t)B_*C_*N_*2;      // 8 MB
  unsigned short* wqb   = (unsigned short*)p; p += 32*256*2;
  unsigned short* wkb   = (unsigned short*)p; p += 32*256*2;
  unsigned short* wvb   = (unsigned short*)p; p += 256*256*2;
  float* biasq          = (float*)p;          p += 32*4;
  float* biask          = (float*)p;          p += 32*4;
  float* biasv          = (float*)p;          p += 256*4;
  unsigned short* parti = (unsigned short*)p; p += (size_t)512*16384*2;     // 16 MB
  float* statsg         = (float*)p;          p += (size_t)512*64*2*4;      // 256 KB

  fold_w_kernel<<<256, 256, 0, stream>>>(wq,wk,wv,gq,bq,mq,vq,gk,bk,mk,vk,gv,bv,mv,vv,
                                         wqb,wkb,wvb,biasq,biask,biasv);
  pre_kernel<<<dim3(64,4,3), 256, 0, stream>>>(x1, x2, wqb, wkb, wvb,
                                               biasq, biask, biasv, x1u, Qb, Kb, Vb);
  attn_kernel<<<dim3(64,4,2), 512, 0, stream>>>(Qb, Kb, Vb, parti, statsg);
  combine_kernel<<<dim3(4,64,4), 256, 0, stream>>>(parti, statsg, x1u, gamma, out);
}